// Round 1
// baseline (918.741 us; speedup 1.0000x reference)
//
#include <hip/hip_runtime.h>

#define F_IN 14
#define HID 64

// ---- degree ----
__global__ void k_deg_init(float* __restrict__ deg, int n) {
    int i = blockIdx.x * blockDim.x + threadIdx.x;
    if (i < n) deg[i] = 1.0f;  // self-loop contribution
}

__global__ void k_deg_edges(const int* __restrict__ dst, float* __restrict__ deg, int e) {
    int i = blockIdx.x * blockDim.x + threadIdx.x;
    if (i < e) atomicAdd(&deg[dst[i]], 1.0f);
}

__global__ void k_dinv(float* __restrict__ deg, int n) {
    int i = blockIdx.x * blockDim.x + threadIdx.x;
    if (i < n) deg[i] = rsqrtf(deg[i]);  // deg >= 1 always (self-loop)
}

// ---- h = x @ W1 ----
__global__ void k_xform(const float* __restrict__ x, const float* __restrict__ W1,
                        float* __restrict__ h, int n) {
    __shared__ float ws[F_IN * HID];
    int t = threadIdx.x;
    for (int i = t; i < F_IN * HID; i += 256) ws[i] = W1[i];
    __syncthreads();
    int node = blockIdx.x * 4 + (t >> 6);
    int lane = t & 63;
    if (node < n) {
        const float* xr = x + (size_t)node * F_IN;
        float acc = 0.f;
#pragma unroll
        for (int f = 0; f < F_IN; ++f) acc += xr[f] * ws[f * HID + lane];
        h[(size_t)node * HID + lane] = acc;
    }
}

// ---- agg init with self-loop term: agg[i] = h[i] * dinv[i]^2 ----
__global__ void k_agg_init(const float* __restrict__ h, const float* __restrict__ dinv,
                           float* __restrict__ agg, int n) {
    int i = blockIdx.x * blockDim.x + threadIdx.x;
    if (i < n * HID) {
        float di = dinv[i >> 6];
        agg[i] = h[i] * di * di;
    }
}

// ---- edge scatter: one wave (64 lanes) per edge ----
__global__ void k_scatter(const int* __restrict__ src, const int* __restrict__ dst,
                          const float* __restrict__ h, const float* __restrict__ dinv,
                          float* __restrict__ agg, int e) {
    int gid = blockIdx.x * blockDim.x + threadIdx.x;
    int eid = gid >> 6;
    int lane = gid & 63;
    if (eid < e) {
        int s = src[eid];
        int d = dst[eid];
        float norm = dinv[s] * dinv[d];
        atomicAdd(&agg[(size_t)d * HID + lane], h[(size_t)s * HID + lane] * norm);
    }
}

// ---- epilogue: out[n] = relu(agg[n] + b1) . W2 + b2 ----
__global__ void k_out(const float* __restrict__ agg, const float* __restrict__ b1,
                      const float* __restrict__ W2, const float* __restrict__ b2,
                      float* __restrict__ out, int n) {
    int gid = blockIdx.x * blockDim.x + threadIdx.x;
    int node = gid >> 6;
    int lane = gid & 63;
    if (node < n) {
        float v = agg[(size_t)node * HID + lane] + b1[lane];
        v = fmaxf(v, 0.f) * W2[lane];
#pragma unroll
        for (int off = 32; off > 0; off >>= 1) v += __shfl_down(v, off, 64);
        if (lane == 0) out[node] = v + b2[0];
    }
}

extern "C" void kernel_launch(void* const* d_in, const int* in_sizes, int n_in,
                              void* d_out, int out_size, void* d_ws, size_t ws_size,
                              hipStream_t stream) {
    const float* x  = (const float*)d_in[0];
    const int*   ei = (const int*)d_in[1];
    const float* W1 = (const float*)d_in[2];
    const float* b1 = (const float*)d_in[3];
    const float* W2 = (const float*)d_in[4];
    const float* b2 = (const float*)d_in[5];
    float* out = (float*)d_out;

    int n = in_sizes[0] / F_IN;
    int e = in_sizes[1] / 2;
    const int* src = ei;
    const int* dst = ei + e;

    float* h    = (float*)d_ws;                  // n*64 floats
    float* agg  = h + (size_t)n * HID;           // n*64 floats
    float* dinv = agg + (size_t)n * HID;         // n floats

    const int B = 256;

    // degree (self-loops folded into init)
    k_deg_init<<<(n + B - 1) / B, B, 0, stream>>>(dinv, n);
    k_deg_edges<<<(e + B - 1) / B, B, 0, stream>>>(dst, dinv, e);
    k_dinv<<<(n + B - 1) / B, B, 0, stream>>>(dinv, n);

    // h = x @ W1
    k_xform<<<(n + 3) / 4, B, 0, stream>>>(x, W1, h, n);

    // agg = self-loop contribution
    k_agg_init<<<((size_t)n * HID + B - 1) / B, B, 0, stream>>>(h, dinv, agg, n);

    // scatter edges: one wave per edge
    long long tot = (long long)e * HID;
    k_scatter<<<(tot + B - 1) / B, B, 0, stream>>>(src, dst, h, dinv, agg, e);

    // epilogue
    k_out<<<((long long)n * HID + B - 1) / B, B, 0, stream>>>(agg, b1, W2, b2, out, n);
}

// Round 2
// 574.123 us; speedup vs baseline: 1.6003x; 1.6003x over previous
//
#include <hip/hip_runtime.h>

#define F_IN 14
#define HID 64
#define SCAN_B 1024  // elements per scan block (256 threads x 4)

// ---------- CSR build ----------
__global__ void k_zero_cnt(int* __restrict__ cnt, int n) {
    int i = blockIdx.x * blockDim.x + threadIdx.x;
    if (i < n) cnt[i] = 0;
}

__global__ void k_count(const int* __restrict__ dst, int* __restrict__ cnt, int e) {
    int i = blockIdx.x * blockDim.x + threadIdx.x;
    if (i < e) atomicAdd(&cnt[dst[i]], 1);
}

// per-block exclusive scan of cnt -> row_ptr (partial), block sums, and dinv
__global__ void k_scan1(const int* __restrict__ cnt, int* __restrict__ row_ptr,
                        int* __restrict__ bsum, float* __restrict__ dinv, int n) {
    __shared__ int ts[256];
    int blk = blockIdx.x, t = threadIdx.x;
    int base = blk * SCAN_B + t * 4;
    int v[4];
    int loc = 0;
#pragma unroll
    for (int j = 0; j < 4; ++j) {
        int idx = base + j;
        int c = (idx < n) ? cnt[idx] : 0;
        v[j] = loc;
        loc += c;
        if (idx < n) dinv[idx] = rsqrtf((float)(c + 1));  // +1 = self-loop
    }
    ts[t] = loc;
    __syncthreads();
    for (int off = 1; off < 256; off <<= 1) {
        int add = (t >= off) ? ts[t - off] : 0;
        __syncthreads();
        ts[t] += add;
        __syncthreads();
    }
    int texcl = (t > 0) ? ts[t - 1] : 0;
#pragma unroll
    for (int j = 0; j < 4; ++j) {
        int idx = base + j;
        if (idx < n) row_ptr[idx] = texcl + v[j];
    }
    if (t == 255) bsum[blk] = ts[255];
}

__global__ void k_scan2(int* __restrict__ bsum, int nb) {
    if (blockIdx.x == 0 && threadIdx.x == 0) {
        int acc = 0;
        for (int i = 0; i < nb; ++i) {
            int v = bsum[i];
            bsum[i] = acc;
            acc += v;
        }
    }
}

__global__ void k_scan3(int* __restrict__ row_ptr, int* __restrict__ cursor,
                        const int* __restrict__ bsum, int n, int e) {
    int i = blockIdx.x * blockDim.x + threadIdx.x;
    if (i < n) {
        int v = row_ptr[i] + bsum[i / SCAN_B];
        row_ptr[i] = v;
        cursor[i] = v;
    }
    if (i == 0) row_ptr[n] = e;
}

__global__ void k_fill(const int* __restrict__ src, const int* __restrict__ dst,
                       int* __restrict__ cursor, int* __restrict__ ssrc, int e) {
    int i = blockIdx.x * blockDim.x + threadIdx.x;
    if (i < e) {
        int d = dst[i];
        int pos = atomicAdd(&cursor[d], 1);
        ssrc[pos] = src[i];
    }
}

// ---------- h = x @ W1 ----------
__global__ void k_xform(const float* __restrict__ x, const float* __restrict__ W1,
                        float* __restrict__ h, int n) {
    __shared__ float ws[F_IN * HID];
    int t = threadIdx.x;
    for (int i = t; i < F_IN * HID; i += 256) ws[i] = W1[i];
    __syncthreads();
    int node = blockIdx.x * 4 + (t >> 6);
    int lane = t & 63;
    if (node < n) {
        const float* xr = x + (size_t)node * F_IN;
        float acc = 0.f;
#pragma unroll
        for (int f = 0; f < F_IN; ++f) acc += xr[f] * ws[f * HID + lane];
        h[(size_t)node * HID + lane] = acc;
    }
}

// ---------- fused gather-aggregate + epilogue: one wave per node ----------
__global__ void k_aggout(const float* __restrict__ h, const float* __restrict__ dinv,
                         const int* __restrict__ row_ptr, const int* __restrict__ ssrc,
                         const float* __restrict__ b1, const float* __restrict__ W2,
                         const float* __restrict__ b2, float* __restrict__ out, int n) {
    int gid = blockIdx.x * blockDim.x + threadIdx.x;
    int node = gid >> 6;
    int lane = gid & 63;
    if (node >= n) return;
    int beg = row_ptr[node];
    int end = row_ptr[node + 1];
    float dn = dinv[node];
    float acc = h[(size_t)node * HID + lane] * dn * dn;  // self-loop
    int i = beg;
    for (; i + 4 <= end; i += 4) {
        int s0 = ssrc[i], s1 = ssrc[i + 1], s2 = ssrc[i + 2], s3 = ssrc[i + 3];
        float w0 = dinv[s0], w1 = dinv[s1], w2 = dinv[s2], w3 = dinv[s3];
        float h0 = h[(size_t)s0 * HID + lane];
        float h1 = h[(size_t)s1 * HID + lane];
        float h2 = h[(size_t)s2 * HID + lane];
        float h3 = h[(size_t)s3 * HID + lane];
        acc += h0 * (w0 * dn);
        acc += h1 * (w1 * dn);
        acc += h2 * (w2 * dn);
        acc += h3 * (w3 * dn);
    }
    for (; i < end; ++i) {
        int s = ssrc[i];
        acc += h[(size_t)s * HID + lane] * (dinv[s] * dn);
    }
    float v = fmaxf(acc + b1[lane], 0.f) * W2[lane];
#pragma unroll
    for (int off = 32; off > 0; off >>= 1) v += __shfl_down(v, off, 64);
    if (lane == 0) out[node] = v + b2[0];
}

extern "C" void kernel_launch(void* const* d_in, const int* in_sizes, int n_in,
                              void* d_out, int out_size, void* d_ws, size_t ws_size,
                              hipStream_t stream) {
    const float* x  = (const float*)d_in[0];
    const int*   ei = (const int*)d_in[1];
    const float* W1 = (const float*)d_in[2];
    const float* b1 = (const float*)d_in[3];
    const float* W2 = (const float*)d_in[4];
    const float* b2 = (const float*)d_in[5];
    float* out = (float*)d_out;

    int n = in_sizes[0] / F_IN;
    int e = in_sizes[1] / 2;
    const int* src = ei;
    const int* dst = ei + e;

    // workspace layout
    float* h       = (float*)d_ws;                    // n*HID f32
    float* dinv    = h + (size_t)n * HID;             // n f32
    int*   cnt     = (int*)(dinv + n);                // n i32
    int*   row_ptr = cnt + n;                         // n+1 i32
    int*   cursor  = row_ptr + (n + 1);               // n i32
    int*   bsum    = cursor + n;                      // ~n/SCAN_B i32
    int*   ssrc    = bsum + 1024;                     // e i32

    const int B = 256;
    int nb = (n + SCAN_B - 1) / SCAN_B;

    k_zero_cnt<<<(n + B - 1) / B, B, 0, stream>>>(cnt, n);
    k_count<<<(e + B - 1) / B, B, 0, stream>>>(dst, cnt, e);
    k_scan1<<<nb, B, 0, stream>>>(cnt, row_ptr, bsum, dinv, n);
    k_scan2<<<1, 64, 0, stream>>>(bsum, nb);
    k_scan3<<<(n + B - 1) / B, B, 0, stream>>>(row_ptr, cursor, bsum, n, e);
    k_fill<<<(e + B - 1) / B, B, 0, stream>>>(src, dst, cursor, ssrc, e);

    k_xform<<<(n + 3) / 4, B, 0, stream>>>(x, W1, h, n);

    long long tot = (long long)n * HID;
    k_aggout<<<(tot + B - 1) / B, B, 0, stream>>>(h, dinv, row_ptr, ssrc, b1, W2, b2, out, n);
}